// Round 14
// baseline (122.977 us; speedup 1.0000x reference)
//
#include <hip/hip_runtime.h>

#define NB 8
#define CHW 6300
#define TT 500
#define OUT 128
#define NO 1024
#define NWORD 197        // ceil(6300/32)
#define XBSTRIDE 256     // padded words per (n,t)

// ---------------- Kernel 1: transpose W[OUT][CHW] -> Wt[CHW][OUT] fp32 ----------------
__global__ __launch_bounds__(256) void packWt(const float* __restrict__ W,
                                              float* __restrict__ Wt) {
    __shared__ float tile[32][33];
    int bc = blockIdx.x * 32;
    int bo = blockIdx.y * 32;
    int tx = threadIdx.x;
    int ty = threadIdx.y;
#pragma unroll
    for (int k = 0; k < 4; k++) {
        int o = bo + ty + k * 8;
        int c = bc + tx;
        float v = (c < CHW) ? W[(size_t)o * CHW + c] : 0.f;
        tile[ty + k * 8][tx] = v;
    }
    __syncthreads();
#pragma unroll
    for (int k = 0; k < 4; k++) {
        int c = bc + ty + k * 8;
        int o = bo + tx;
        if (c < CHW) Wt[(size_t)c * OUT + o] = tile[tx][ty + k * 8];
    }
}

// ---------------- Kernel 2: bitpack x -> xb[n*TT+t][word] ----------------
// Block (cs,tb,n): words [cs*25, min(cs*25+25,197)), t [tb*64, +64).
// Per 4-word group: stage 128c x 64t fp32 tile coalesced into LDS, then wave w
// packs word g+w (lane = t): bit i = (x[n][c][t] != 0).
__global__ __launch_bounds__(256) void bitpack(const float* __restrict__ x,
                                               unsigned* __restrict__ xb) {
    const int cs = blockIdx.x;        // 0..7
    const int tb = blockIdx.y;        // 0..7
    const int n  = blockIdx.z;        // 0..7
    const int tid = threadIdx.x;
    const int wv4 = tid >> 6;
    const int lane = tid & 63;
    const int t0 = tb * 64;
    const int w0 = cs * 25;
    const int wend = min(w0 + 25, NWORD);

    __shared__ float xs[4][32][65];   // 33.3KB

    const float* xn = x + (size_t)n * CHW * TT;
    const int ch = tid & 15;          // t-chunk (4 floats)
    const int rb = tid >> 4;          // 0..15
    const bool t_ok = (tb < 7) || (ch < 13);   // full float4 stays < t=500

    for (int g = w0; g < wend; g += 4) {
#pragma unroll
        for (int k = 0; k < 8; ++k) {
            int rloc = rb + 16 * k;               // 0..127
            int wq = rloc >> 5;                   // word-in-group 0..3
            int c = (g + wq) * 32 + (rloc & 31);
            float4 v = make_float4(0.f, 0.f, 0.f, 0.f);
            if ((g + wq) < wend && c < CHW && t_ok)
                v = *(const float4*)(xn + (size_t)c * TT + t0 + ch * 4);
            xs[wq][rloc & 31][ch * 4 + 0] = v.x;
            xs[wq][rloc & 31][ch * 4 + 1] = v.y;
            xs[wq][rloc & 31][ch * 4 + 2] = v.z;
            xs[wq][rloc & 31][ch * 4 + 3] = v.w;
        }
        __syncthreads();
        int wi = g + wv4;
        int t = t0 + lane;
        if (wi < wend && t < TT) {
            unsigned bits = 0;
#pragma unroll
            for (int i = 0; i < 32; ++i)
                bits |= (xs[wv4][i][lane] != 0.f ? 1u : 0u) << i;
            xb[(size_t)(n * TT + t) * XBSTRIDE + wi] = bits;
        }
        __syncthreads();
    }
}

// ---------------- Kernel 3: sparse projection ----------------
// One 64-lane wave per (n,t): v[o] = sum over set bits c of Wt[c][o].
// Mask words broadcast via shfl+readfirstlane (uniform scalar loop); per set
// bit one coalesced 512B row load; 4-way unroll = 4 loads in flight, 4
// independent fp32 accumulator pairs. Skipping zeros is EXACT in fp32.
__global__ __launch_bounds__(64) void spgemm(const unsigned* __restrict__ xb,
                                             const float* __restrict__ Wt,
                                             float* __restrict__ vred) {
    const int t = blockIdx.x;
    const int n = blockIdx.y;
    const int lane = threadIdx.x;
    const unsigned* mp = xb + (size_t)(n * TT + t) * XBSTRIDE;
    unsigned vm0 = mp[lane];
    unsigned vm1 = mp[64 + lane];
    unsigned vm2 = mp[128 + lane];
    unsigned vm3 = mp[192 + lane];

    float aA0 = 0.f, aA1 = 0.f, aB0 = 0.f, aB1 = 0.f;
    float aC0 = 0.f, aC1 = 0.f, aD0 = 0.f, aD1 = 0.f;

#define CHUNK(wlo_, whi_, cb_)                                                      \
    {                                                                               \
        unsigned long long wv = (unsigned long long)(wlo_) |                        \
                                ((unsigned long long)(whi_) << 32);                 \
        while (wv) {                                                                \
            int bA = __builtin_ctzll(wv); wv &= wv - 1;                             \
            int hB = (wv != 0); int bB = hB ? __builtin_ctzll(wv) : bA;             \
            wv = hB ? (wv & (wv - 1)) : 0ull;                                       \
            int hC = (wv != 0); int bC = hC ? __builtin_ctzll(wv) : bA;             \
            wv = hC ? (wv & (wv - 1)) : 0ull;                                       \
            int hD = (wv != 0); int bD = hD ? __builtin_ctzll(wv) : bA;             \
            wv = hD ? (wv & (wv - 1)) : 0ull;                                       \
            float2 wA = *(const float2*)(Wt + (size_t)((cb_) + bA) * OUT + lane * 2); \
            float2 wB = *(const float2*)(Wt + (size_t)((cb_) + bB) * OUT + lane * 2); \
            float2 wC = *(const float2*)(Wt + (size_t)((cb_) + bC) * OUT + lane * 2); \
            float2 wD = *(const float2*)(Wt + (size_t)((cb_) + bD) * OUT + lane * 2); \
            float sB = hB ? 1.f : 0.f, sC = hC ? 1.f : 0.f, sD = hD ? 1.f : 0.f;    \
            aA0 += wA.x; aA1 += wA.y;                                               \
            aB0 = fmaf(sB, wB.x, aB0); aB1 = fmaf(sB, wB.y, aB1);                   \
            aC0 = fmaf(sC, wC.x, aC0); aC1 = fmaf(sC, wC.y, aC1);                   \
            aD0 = fmaf(sD, wD.x, aD0); aD1 = fmaf(sD, wD.y, aD1);                   \
        }                                                                           \
    }

#define RD(vm, idx) (unsigned)__builtin_amdgcn_readfirstlane(__shfl((int)(vm), (idx)))

    for (int jj = 0; jj < 32; ++jj) {
        unsigned lo = RD(vm0, jj * 2);
        unsigned hi = RD(vm0, jj * 2 + 1);
        CHUNK(lo, hi, jj * 64)
    }
    for (int jj = 0; jj < 32; ++jj) {
        unsigned lo = RD(vm1, jj * 2);
        unsigned hi = RD(vm1, jj * 2 + 1);
        CHUNK(lo, hi, 2048 + jj * 64)
    }
    for (int jj = 0; jj < 32; ++jj) {
        unsigned lo = RD(vm2, jj * 2);
        unsigned hi = RD(vm2, jj * 2 + 1);
        CHUNK(lo, hi, 4096 + jj * 64)
    }
    for (int jj = 0; jj < 3; ++jj) {    // words 192..196 (197 total)
        unsigned lo = RD(vm3, jj * 2);
        unsigned hi = (jj < 2) ? RD(vm3, jj * 2 + 1) : 0u;
        CHUNK(lo, hi, 6144 + jj * 64)
    }
#undef CHUNK
#undef RD

    float r0 = (aA0 + aB0) + (aC0 + aD0);
    float r1 = (aA1 + aB1) + (aC1 + aD1);
    *(float2*)(vred + ((size_t)t * NB + n) * OUT + lane * 2) = make_float2(r0, r1);
}

// ---------------- Kernel 4: wave-specialized alpha+spike scan ----------------
// 32 blocks x 512 thr, 32 chains/block. Wave 0 (lanes 0-31): serial G/H
// recursion; waves 1-7: stage next vred slab into vbuf[t][chain].
#define SCN_RA 0.9048374180359595f       // exp(-0.1)
#define SCN_RACA 0.24596031111569496f    // RA*CA = 0.1*e^0.9
#define SCN_RS 0.36787944117144233f      // exp(-1)
#define SCN_RSCS -20.0f                  // RS*CS (CS = -20e)
#define SCN_RSCS2 -40.0f                 // 2*RS*CS
#define SCN_RSRSCS -7.3575888234288467f  // RS*RS*CS
#define SCN_TH 10.0f

#define CHAIN_STEP(i)                                                   \
    {                                                                   \
        float ua = Aa;                                                  \
        float w = fmaf(SCN_RS, G, ua);                                  \
        float u = sp ? (w + SCN_RSCS) : w;                              \
        bool sn = (u >= SCN_TH);                                        \
        sbuf[i][lane] = sn ? 1.f : 0.f;                                 \
        float Gb = fmaf(SCN_RS, G, H);                                  \
        G = sp ? (Gb + SCN_RSCS2) : Gb;                                 \
        float Hb = SCN_RS * H;                                          \
        H = sp ? (Hb + SCN_RSRSCS) : Hb;                                \
        sp = sn;                                                        \
        Ba = fmaf(SCN_RA, Ba, SCN_RACA * vv[i]);                        \
        Aa = fmaf(SCN_RA, Aa, Ba);                                      \
    }

__global__ __launch_bounds__(512) void scanspike(const float* __restrict__ vred,
                                                 float* __restrict__ out) {
    const int tid = threadIdx.x;
    const int wave = tid >> 6;
    const int lane = tid & 63;
    const int l5 = lane & 31;
    const int rh = lane >> 5;
    const int g0 = blockIdx.x * 32;
    const int cn = g0 >> 7;
    const int co = (g0 & 127) + l5;

    __shared__ float vbuf[2][64][32];
    __shared__ float sbuf[64][33];

    for (int rp = wave; rp * 2 < 64; rp += 8) {
        int r = rp * 2 + rh;
        vbuf[0][r][l5] = vred[((size_t)r * NB + cn) * OUT + co];
    }
    __syncthreads();

    float Aa = 0.f, Ba = 0.f, G = 0.f, H = 0.f;
    bool sp = false;

    for (int tb = 0; tb < 8; ++tb) {
        const int cur = tb & 1;
        const int t0 = tb * 64;
        const int cnt = (tb == 7) ? 52 : 64;

        if (wave == 0) {
            if (lane < 32) {
                if (cnt == 64) {
                    float vv[64];
#pragma unroll
                    for (int i = 0; i < 64; ++i) vv[i] = vbuf[cur][i][l5];
#pragma unroll
                    for (int i = 0; i < 64; ++i) CHAIN_STEP(i)
                } else {
                    float vv[52];
#pragma unroll
                    for (int i = 0; i < 52; ++i) vv[i] = vbuf[cur][i][l5];
#pragma unroll
                    for (int i = 0; i < 52; ++i) CHAIN_STEP(i)
                }
            }
        } else if (tb < 7) {
            const int nt0 = t0 + 64;
            const int ncnt = (tb == 6) ? 52 : 64;
            for (int rp = wave - 1; rp * 2 < ncnt; rp += 7) {
                int r = rp * 2 + rh;
                vbuf[cur ^ 1][r][l5] = vred[((size_t)(nt0 + r) * NB + cn) * OUT + co];
            }
        }
        __syncthreads();

#pragma unroll
        for (int j = 0; j < 4; ++j) {
            int cc = wave * 4 + j;
            int oo = (g0 & 127) + cc;
            if (lane < cnt)
                out[((size_t)cn * OUT + oo) * TT + t0 + lane] = sbuf[lane][cc];
        }
        __syncthreads();
    }
}

extern "C" void kernel_launch(void* const* d_in, const int* in_sizes, int n_in,
                              void* d_out, int out_size, void* d_ws, size_t ws_size,
                              hipStream_t stream) {
    const float* x = (const float*)d_in[0];   // [8,2,50,63,500] fp32
    const float* W = (const float*)d_in[1];   // [128,6300] fp32
    float* out = (float*)d_out;               // [8,128,1,1,500] fp32

    float*    Wt   = (float*)d_ws;                                   // 3,225,600 B
    unsigned* xb   = (unsigned*)((char*)d_ws + 3225600);             // 4,096,000 B
    float*    vred = (float*)((char*)d_ws + 3225600 + 4096000);      // 2,048,000 B

    packWt<<<dim3((CHW + 31) / 32, OUT / 32), dim3(32, 8), 0, stream>>>(W, Wt);
    bitpack<<<dim3(8, 8, 8), 256, 0, stream>>>(x, xb);
    spgemm<<<dim3(TT, NB), 64, 0, stream>>>(xb, Wt, vred);
    scanspike<<<32, 512, 0, stream>>>(vred, out);
}